// Round 1
// 430.535 us; speedup vs baseline: 1.2076x; 1.2076x over previous
//
#include <hip/hip_runtime.h>

#define T_LEN 1024
#define B_SZ  4096
#define CHUNK 32                      // timesteps per LDS ring buffer
#define NCHUNK (T_LEN / CHUNK)        // 32 chunks

// DPP controls (gfx9/CDNA).
// quad_perm xor patterns + broadcasts are direction-unambiguous.
// row_ror convention VERIFIED BY EVIDENCE (prior rounds): ror:12 reads lane+4,
// ror:8 reads lane+8, ror:4 reads lane+12. row_shr scan (lane i reads i-n)
// anchored by LLVM AMDGPUAtomicOptimizer.
#define DPP_QP(a,b,c,d) ((a)|((b)<<2)|((c)<<4)|((d)<<6))
#define DPP_QPX1 DPP_QP(1,0,3,2)   // lane ^ 1 (within quad)
#define DPP_QPX2 DPP_QP(2,3,0,1)   // lane ^ 2
#define DPP_QPX3 DPP_QP(3,2,1,0)   // lane ^ 3
#define DPP_BCAST0 DPP_QP(0,0,0,0) // all quad lanes read quad lane 0
#define DPP_BCAST1 DPP_QP(1,1,1,1)
#define DPP_BCAST2 DPP_QP(2,2,2,2)
#define DPP_BCAST3 DPP_QP(3,3,3,3)
#define DPP_ROW_SHR(n) (0x110|(n))
#define DPP_ROW_ROR(n) (0x120|(n))

template <int CTRL>
__device__ __forceinline__ float dppf(float x) {
  return __int_as_float(__builtin_amdgcn_update_dpp(
      0, __float_as_int(x), CTRL, 0xF, 0xF, true));
}
// Scan helper: invalid source lanes receive identity 1.0f (old operand,
// bound_ctrl=false => keep old). Removes the (w>=k) cndmask guards.
template <int CTRL>
__device__ __forceinline__ float dppf_id1(float x) {
  return __int_as_float(__builtin_amdgcn_update_dpp(
      0x3f800000, __float_as_int(x), CTRL, 0xF, 0xF, false));
}

// Lane layout within each 16-lane group (one batch element):
//   lane16 = w*4 + g   (w = wire/hidden 0..3 bits[3:2],
//                       g = gate 0=f,1=i,2=g,3=o AND x-quarter, bits[1:0])
// qlayer closed form: out_w = prod_{j<=w} cos(theta_j), theta = W.[x,h]+b+phi
//
// Producer/consumer split (this round): wave 1 computes the h-independent
// zx = fract((W_x.x + b + phi)/2pi) per (gate,wire,batch) lane and streams it
// into a double-buffered LDS ring; wave 0 runs the serial recurrence only.
// All angles are carried in REVOLUTIONS (weights pre-scaled by 1/2pi) so the
// consumer chain needs neither the *inv2pi multiply nor the fract:
// cos input = fract(zx) + zh_rev  in (-0.3, 1.3), valid for v_cos.
__global__ void __launch_bounds__(128, 2) qlstm_65481071402744_kernel(
    const float* __restrict__ x,
    const float* __restrict__ Wf, const float* __restrict__ bfv,
    const float* __restrict__ Wi, const float* __restrict__ biv,
    const float* __restrict__ Wg, const float* __restrict__ bgv,
    const float* __restrict__ Wo, const float* __restrict__ bov,
    const float* __restrict__ rxf, const float* __restrict__ rxi,
    const float* __restrict__ rxg, const float* __restrict__ rxo,
    float* __restrict__ out) {
  __shared__ float zbuf[2][CHUNK][64];  // 16 KiB, lane-consecutive dwords

  const int tid = threadIdx.x;
  const int lane = tid & 63;
  const int g = lane & 3;         // gate index AND x-quarter index
  const int w = (lane >> 2) & 3;  // wire index
  const int b = (blockIdx.x << 2) + (lane >> 4);  // batch element

  auto Wsel = [&](int gg) -> const float* {
    return gg == 0 ? Wf : gg == 1 ? Wi : gg == 2 ? Wg : Wo;
  };
  const float* bown = g == 0 ? bfv : g == 1 ? biv : g == 2 ? bgv : bov;
  const float* rxown = g == 0 ? rxf : g == 1 ? rxi : g == 2 ? rxg : rxo;
  constexpr float INV2PI = 0.15915494309189535f;

  if (tid >= 64) {
    // ---------------- producer wave: x-projection in revolutions ----------
    // x-part weights: lane (w,g) computes p[j] = partial of (gate g^j, wire w)
    // over x-quarter [4g, 4g+4). xor-reduce brings all quarters to gate g's
    // lane. Pre-scaled by 1/2pi.
    float Wxp[4][4];
#pragma unroll
    for (int j = 0; j < 4; ++j) {
      const float* Wt = Wsel(g ^ j);
#pragma unroll
      for (int d = 0; d < 4; ++d)
        Wxp[j][d] = Wt[w * 20 + (g << 2) + d] * INV2PI;
    }
    const float zinit = (bown[w] + rxown[w]) * INV2PI;  // bias + RX phase

    // 8-deep register prefetch ring of this lane's x-quarter. Producer has
    // ~2.5x slack vs consumer, so even partial latency exposure is hidden.
    const float4* xp4 = (const float4*)x + ((size_t)b << 2) + g;
    float4 xr[8];
#pragma unroll
    for (int u = 0; u < 8; ++u) xr[u] = xp4[(size_t)u * (B_SZ * 4)];

    for (int c = 0; c < NCHUNK; ++c) {
      float* zb = &zbuf[c & 1][0][0];
#pragma unroll
      for (int qq = 0; qq < CHUNK / 8; ++qq) {
#pragma unroll
        for (int u = 0; u < 8; ++u) {
          const int tloc = (qq << 3) + u;
          const int t = c * CHUNK + tloc;
          const float4 xq = xr[u];
          int tl = t + 8;
          tl = tl < T_LEN ? tl : T_LEN - 1;  // clamped tail prefetch
          xr[u] = xp4[(size_t)tl * (B_SZ * 4)];

          // partial dots over this lane's x-quarter for gates g^j
          float p0 = fmaf(Wxp[0][0], xq.x, zinit);
          p0 = fmaf(Wxp[0][1], xq.y, p0);
          p0 = fmaf(Wxp[0][2], xq.z, p0);
          p0 = fmaf(Wxp[0][3], xq.w, p0);
          float p1 = fmaf(Wxp[1][3], xq.w,
                     fmaf(Wxp[1][2], xq.z,
                     fmaf(Wxp[1][1], xq.y, Wxp[1][0] * xq.x)));
          float p2 = fmaf(Wxp[2][3], xq.w,
                     fmaf(Wxp[2][2], xq.z,
                     fmaf(Wxp[2][1], xq.y, Wxp[2][0] * xq.x)));
          float p3 = fmaf(Wxp[3][3], xq.w,
                     fmaf(Wxp[3][2], xq.z,
                     fmaf(Wxp[3][1], xq.y, Wxp[3][0] * xq.x)));

          // xor rotate-reduce within quad: full x-dot + bias + phase (rev)
          const float zx = (p0 + dppf<DPP_QPX1>(p1)) +
                           (dppf<DPP_QPX2>(p2) + dppf<DPP_QPX3>(p3));
          // pre-fract: cos is 1-periodic in revolutions, consumer adds only
          // the small |zh| < ~0.2 rev recurrent term.
          zb[tloc * 64 + lane] = __builtin_amdgcn_fractf(zx);
        }
      }
      __syncthreads();  // barrier c: chunk c published
    }
  } else {
    // ---------------- consumer wave: serial recurrence -------------------
    // h-part weights for rotate-gather, pre-scaled to revolutions.
    const float* Wown = Wsel(g);
    float Whs[4];
#pragma unroll
    for (int k = 0; k < 4; ++k)
      Whs[k] = Wown[w * 20 + 16 + ((w + k) & 3)] * INV2PI;

    constexpr float L2E = 1.4426950408889634f;
    const bool isG = (g == 2);                      // tanh gate
    const float nlscale = isG ? -2.0f * L2E : -L2E; // exp2 scale
    const float nla = isG ? 2.0f : 1.0f;            // post-rcp fma a
    const float nlb = isG ? -1.0f : 0.0f;           // post-rcp fma b

    float hx = 0.0f, cx = 0.0f;
    float* outp = out + ((size_t)b << 2) + w;

    for (int c = 0; c < NCHUNK; ++c) {
      __syncthreads();  // barrier c: wait for chunk c
      const float* zb = &zbuf[c & 1][0][0];
#pragma unroll
      for (int qq = 0; qq < CHUNK / 8; ++qq) {
        float hb[8];
#pragma unroll
        for (int u = 0; u < 8; ++u) {
          const int tloc = (qq << 3) + u;
          const float zxf = zb[tloc * 64 + lane];  // h-independent part (rev)

          // recurrent dot: single-hop rotations (independent), depth-3 tree
          const float h1 = dppf<DPP_ROW_ROR(12)>(hx);  // h_{w+1}
          const float h2 = dppf<DPP_ROW_ROR(8)>(hx);   // h_{w+2}
          const float h3 = dppf<DPP_ROW_ROR(4)>(hx);   // h_{w+3}
          float za = fmaf(Whs[0], hx, zxf);
          za = fmaf(Whs[1], h1, za);
          const float zb2 = fmaf(Whs[3], h3, Whs[2] * h2);
          const float z = za + zb2;  // in (-0.3, 1.3) revolutions

          const float ccos = __builtin_amdgcn_cosf(z);

          // inclusive cumprod over w: row_shr scan with identity-1 fill
          float q = ccos * dppf_id1<DPP_ROW_SHR(4)>(ccos);
          q = q * dppf_id1<DPP_ROW_SHR(8)>(q);

          // sigmoid (f,i,o) / tanh (g) via exp2+rcp, per-lane consts
          const float ee = __builtin_amdgcn_exp2f(q * nlscale);
          const float s = fmaf(__builtin_amdgcn_rcpf(1.0f + ee), nla, nlb);

          // gate all-gather: quad broadcasts
          const float fA = dppf<DPP_BCAST0>(s);
          const float iA = dppf<DPP_BCAST1>(s);
          const float gA = dppf<DPP_BCAST2>(s);
          const float oA = dppf<DPP_BCAST3>(s);

          cx = fmaf(fA, cx, iA * gA);
          const float e3 = __builtin_amdgcn_exp2f(cx * (-2.0f * L2E));
          const float th = fmaf(2.0f, __builtin_amdgcn_rcpf(1.0f + e3), -1.0f);
          hx = oA * th;
          hb[u] = hx;
        }
        // store burst: one exec-mask section per 8 timesteps
        if (g == 0) {
          const int tbase = c * CHUNK + (qq << 3);
#pragma unroll
          for (int u = 0; u < 8; ++u)
            outp[(size_t)(tbase + u) * (B_SZ * 4)] = hb[u];
        }
      }
    }

    if (g == 0) {
      const size_t base = (size_t)T_LEN * B_SZ * 4;
      out[base + (b << 2) + w] = hx;               // final hx
      out[base + B_SZ * 4 + (b << 2) + w] = cx;    // final cx
    }
  }
}

extern "C" void kernel_launch(void* const* d_in, const int* in_sizes, int n_in,
                              void* d_out, int out_size, void* d_ws, size_t ws_size,
                              hipStream_t stream) {
  const float* x   = (const float*)d_in[0];
  const float* Wf  = (const float*)d_in[1];
  const float* bf_ = (const float*)d_in[2];
  const float* Wi  = (const float*)d_in[3];
  const float* bi_ = (const float*)d_in[4];
  const float* Wg  = (const float*)d_in[5];
  const float* bg_ = (const float*)d_in[6];
  const float* Wo  = (const float*)d_in[7];
  const float* bo_ = (const float*)d_in[8];
  const float* rxf = (const float*)d_in[9];
  const float* rxi = (const float*)d_in[10];
  const float* rxg = (const float*)d_in[11];
  const float* rxo = (const float*)d_in[12];

  // 4096 batch / 4 per block = 1024 blocks x 128 threads (2 waves:
  // wave0 = recurrence consumer, wave1 = x-projection producer)
  qlstm_65481071402744_kernel<<<B_SZ / 4, 128, 0, stream>>>(
      x, Wf, bf_, Wi, bi_, Wg, bg_, Wo, bo_, rxf, rxi, rxg, rxo,
      (float*)d_out);
}